// Round 4
// baseline (157.795 us; speedup 1.0000x reference)
//
#include <hip/hip_runtime.h>

typedef _Float16 f16;
typedef __fp16 fp16x2 __attribute__((ext_vector_type(2)));
typedef _Float16 half8 __attribute__((ext_vector_type(8)));
typedef float floatx16 __attribute__((ext_vector_type(16)));

union H8 { half8 v; fp16x2 p[4]; unsigned u[4]; };
union P2 { fp16x2 p; unsigned u; };

// Fused SSIM via MFMA, H-pass then V-pass, fully register-resident (NO LDS).
//   pass1: T_h[r][x] = sum_k g[k-n-3] * X[row r][col x0-8+k]   (two 32-row m-tiles)
//   pass2: OUT^T[x][y] = sum_r g[r-y] * T_h^T[x][r]
// Pass-2 A-fragments are built from pass-1 accumulators by a lane-half swap:
// D layout (32x32 MFMA): row=(reg&3)+8*(reg>>2)+4*(lane>>5), col=lane&31.
// For K-block kb, lane-half h needs rows 16kb+8h+j -> packed dword pairs
// c[s][i]=pk(acc[4s+2i],acc[4s+2i+1]) with s=2kb+h; j>=4 comes from the OTHER
// lane half -> one half-swap (shfl_xor 32 + select) per dword pair.
// Register discipline (round-3 lesson: acc arrays are 64 regs each; granule
// >170 -> 2 waves/SIMD): m1 loads issued only after accT dies into 32 f16
// dwords; band2 rebuilt late from gv. Target peak ~164 <= 170 (3 waves/SIMD).
// Tail: one fire-and-forget atomicAdd per wave (padded buckets); NO fences
// (agent-scope fence = L2 writeback on gfx950, 8x regression measured in r1).
// No clip: |clip(x)-x| <= 1e-6, ~500x below fp16-RTZ noise already present.

__device__ __forceinline__ unsigned pk(float a, float b) {
    P2 t; t.p = __builtin_amdgcn_cvt_pkrtz(a, b); return t.u;
}

// halfswap: r0 = {a.lo-half-own, b.lo-half-from-other}, r1 = {a.hi-from-other, b.hi-own}
__device__ __forceinline__ void halfswap(bool lo, unsigned a, unsigned b,
                                         unsigned &r0, unsigned &r1) {
    unsigned as = (unsigned)__shfl_xor((int)a, 32, 64);
    unsigned bs = (unsigned)__shfl_xor((int)b, 32, 64);
    r0 = lo ? a  : bs;
    r1 = lo ? as : b;
}

__device__ __forceinline__ half8 mkband(float gv, int ib) {
    // B[k=8q+j block][n=ln] = g[ib + j]; lanes >= 11 hold gv = 0 -> zero taps
    H8 t;
    #pragma unroll
    for (int jj = 0; jj < 4; ++jj) {
        float g0 = __shfl(gv, (ib + 2 * jj)     & 63, 64);
        float g1 = __shfl(gv, (ib + 2 * jj + 1) & 63, 64);
        fp16x2 pp = { (__fp16)g0, (__fp16)g1 };
        t.p[jj] = pp;
    }
    return t.v;
}

__device__ __forceinline__ void load_tile(
    const float* __restrict__ img1, const float* __restrict__ img2, size_t base,
    int row, int rowcap, int x0, int q, float4 ra[3][2], float4 rb[3][2], unsigned mk[3])
{
    int rowc = min(max(min(row, rowcap), 0), 511);   // load address (deduped)
    bool rok = (row >= 0) && (row <= 511);           // mask from wanted row
    const float* r1 = img1 + base + (size_t)rowc * 512;
    const float* r2 = img2 + base + (size_t)rowc * 512;
    #pragma unroll
    for (int ch = 0; ch < 3; ++ch) {
        int cb  = x0 - 8 + 16 * ch + 8 * q;      // 8-col chunk, 32B aligned
        int cbc = min(max(cb, 0), 504);
        mk[ch] = (cb == cbc && rok) ? 0xFFFFFFFFu : 0u;
        ra[ch][0] = *(const float4*)(r1 + cbc);
        ra[ch][1] = *(const float4*)(r1 + cbc + 4);
        rb[ch][0] = *(const float4*)(r2 + cbc);
        rb[ch][1] = *(const float4*)(r2 + cbc + 4);
    }
}

__device__ __forceinline__ void compute_acct(
    const float4 ra[3][2], const float4 rb[3][2], const unsigned mk[3],
    const half8 band1[3], floatx16 acc[4])
{
    #pragma unroll
    for (int ch = 0; ch < 3; ++ch) {
        H8 F0, F1, F2, F3;
        #pragma unroll
        for (int h = 0; h < 2; ++h) {
            const float as[4] = {ra[ch][h].x, ra[ch][h].y, ra[ch][h].z, ra[ch][h].w};
            const float bs[4] = {rb[ch][h].x, rb[ch][h].y, rb[ch][h].z, rb[ch][h].w};
            #pragma unroll
            for (int t = 0; t < 2; ++t) {
                float a0 = as[2*t], a1 = as[2*t+1];
                float b0 = bs[2*t], b1 = bs[2*t+1];
                int jj = 2 * h + t;
                F0.p[jj] = __builtin_amdgcn_cvt_pkrtz(a0, a1);
                F1.p[jj] = __builtin_amdgcn_cvt_pkrtz(b0, b1);
                F2.p[jj] = __builtin_amdgcn_cvt_pkrtz(a0*a0 + b0*b0, a1*a1 + b1*b1);
                F3.p[jj] = __builtin_amdgcn_cvt_pkrtz(a0*b0, a1*b1);
            }
        }
        // OOB mask (row clamp / col chunk) as packed AND: {0,1} multiply -> bitmask
        unsigned m = mk[ch];
        #pragma unroll
        for (int i = 0; i < 4; ++i) { F0.u[i] &= m; F1.u[i] &= m; F2.u[i] &= m; F3.u[i] &= m; }
        acc[0] = __builtin_amdgcn_mfma_f32_32x32x16_f16(F0.v, band1[ch], acc[0], 0, 0, 0);
        acc[1] = __builtin_amdgcn_mfma_f32_32x32x16_f16(F1.v, band1[ch], acc[1], 0, 0, 0);
        acc[2] = __builtin_amdgcn_mfma_f32_32x32x16_f16(F2.v, band1[ch], acc[2], 0, 0, 0);
        acc[3] = __builtin_amdgcn_mfma_f32_32x32x16_f16(F3.v, band1[ch], acc[3], 0, 0, 0);
    }
}

__global__ __launch_bounds__(128, 3) void ssim_kernel(
    const float* __restrict__ img1, const float* __restrict__ img2,
    const float* __restrict__ window, float* __restrict__ acc)
{
    const int tid  = threadIdx.x;
    const int lane = tid & 63;
    const int wv   = tid >> 6;
    const int q    = lane >> 5;
    const int ln   = lane & 31;
    const bool lo  = (q == 0);

    const int bz = blockIdx.z;
    const int c  = bz % 3;
    const int x0 = blockIdx.x * 64 + 32 * wv;
    const int oy = blockIdx.y * 32;
    const size_t base = (size_t)bz * (512 * 512);

    // ---- m=0 loads in flight under setup ----
    float4 ra[3][2], rb[3][2]; unsigned mk[3];
    load_tile(img1, img2, base, oy - 5 + ln, 511, x0, q, ra, rb, mk);

    // per-wave 1-D gaussian: lane t<11 holds g[t] = sum_j w2d[t][j]
    float gv = 0.f;
    if (lane < 11) {
        const float* w2 = window + c * 121 + lane * 11;
        #pragma unroll
        for (int j = 0; j < 11; ++j) gv += w2[j];
    }

    half8 band1[3];
    #pragma unroll
    for (int ch = 0; ch < 3; ++ch) band1[ch] = mkband(gv, 16 * ch + 8 * q - ln - 3);

    // ---- pass 1, m=0 (T rows 0..31 = image rows oy-5..oy+26) ----
    floatx16 accT[4] = {};
    compute_acct(ra, rb, mk, band1, accT);

    // issue m=1 loads now (overlap with cvt + band2); rows deduped at oy+36:
    // lanes 10..31 only feed T rows >= 42 which multiply g=0 (finite garbage ok)
    float4 ra1[3][2], rb1[3][2]; unsigned mk1[3];
    load_tile(img1, img2, base, oy + 27 + ln, oy + 36, x0, q, ra1, rb1, mk1);

    // accT -> packed f16 dwords; cT[f][s][i] = rows (2i,2i+1)+8s+4*(lane>>5), col ln
    unsigned cT[4][4][2];
    #pragma unroll
    for (int f = 0; f < 4; ++f)
        #pragma unroll
        for (int s = 0; s < 4; ++s)
            #pragma unroll
            for (int i = 0; i < 2; ++i)
                cT[f][s][i] = pk(accT[f][4*s + 2*i], accT[f][4*s + 2*i + 1]);

    // ---- pass 1, m=1 (T rows 32..63; only 32..43 consumed) ----
    floatx16 accU[4] = {};
    compute_acct(ra1, rb1, mk1, band1, accU);

    unsigned cU[4][2][2];
    #pragma unroll
    for (int f = 0; f < 4; ++f)
        #pragma unroll
        for (int s = 0; s < 2; ++s)
            #pragma unroll
            for (int i = 0; i < 2; ++i)
                cU[f][s][i] = pk(accU[f][4*s + 2*i], accU[f][4*s + 2*i + 1]);

    // band2 built late (register-peak discipline): g[k-n]
    half8 band2[3];
    #pragma unroll
    for (int ch = 0; ch < 3; ++ch) band2[ch] = mkband(gv, 16 * ch + 8 * q - ln);

    // ---- pass 2, register-resident: A[m=x][k=r] via lane-half swaps ----
    floatx16 accH[4] = {};
    #pragma unroll
    for (int kb = 0; kb < 3; ++kb) {
        #pragma unroll
        for (int f = 0; f < 4; ++f) {
            unsigned a0 = (kb < 2) ? cT[f][2*kb][0]     : cU[f][0][0];
            unsigned b0 = (kb < 2) ? cT[f][2*kb + 1][0] : cU[f][1][0];
            unsigned a1 = (kb < 2) ? cT[f][2*kb][1]     : cU[f][0][1];
            unsigned b1 = (kb < 2) ? cT[f][2*kb + 1][1] : cU[f][1][1];
            unsigned d0, d1, d2, d3;
            halfswap(lo, a0, b0, d0, d2);     // k=(0,1)/(8,9) and k=(4,5)/(12,13)
            halfswap(lo, a1, b1, d1, d3);     // k=(2,3)/(10,11) and k=(6,7)/(14,15)
            H8 A; A.u[0] = d0; A.u[1] = d1; A.u[2] = d2; A.u[3] = d3;
            accH[f] = __builtin_amdgcn_mfma_f32_32x32x16_f16(A.v, band2[kb], accH[f], 0, 0, 0);
        }
    }

    // ---- epilogue: all 16 outputs per lane valid (exact tiling) ----
    float vsum = 0.f;
    const float C1 = 1e-4f, C2 = 9e-4f;
    #pragma unroll
    for (int r = 0; r < 16; ++r) {
        float mu1 = accH[0][r], mu2 = accH[1][r];
        float S = accH[2][r], E12 = accH[3][r];
        float mu11 = mu1 * mu1, mu22 = mu2 * mu2, mu12 = mu1 * mu2;
        float num = (2.f * mu12 + C1) * (2.f * (E12 - mu12) + C2);
        float den = (mu11 + mu22 + C1) * (S - mu11 - mu22 + C2);
        vsum += num * __builtin_amdgcn_rcpf(den);
    }

    // wave reduce -> ONE fire-and-forget atomic per wave, padded per-slice bucket
    #pragma unroll
    for (int off = 32; off > 0; off >>= 1) vsum += __shfl_down(vsum, off, 64);
    if (lane == 0) atomicAdd(&acc[bz * 16], vsum);   // 256 adds/bucket, 48 cachelines
}

__global__ void ssim_finalize(const float* __restrict__ acc,
                              float* __restrict__ out, float invN)
{
    const int lane = threadIdx.x;
    float v = (lane < 48) ? acc[lane * 16] : 0.f;
    #pragma unroll
    for (int off = 32; off > 0; off >>= 1) v += __shfl_down(v, off, 64);
    if (lane == 0) out[0] = 1.0f - v * invN;
}

extern "C" void kernel_launch(void* const* d_in, const int* in_sizes, int n_in,
                              void* d_out, int out_size, void* d_ws, size_t ws_size,
                              hipStream_t stream) {
    const float* img1 = (const float*)d_in[0];
    const float* img2 = (const float*)d_in[1];
    const float* window = (const float*)d_in[2];
    float* out = (float*)d_out;
    float* acc = (float*)d_ws;                      // 48 buckets, stride 16 f32 (64 B)

    const float invN = 1.0f / (16.0f * 3.0f * 512.0f * 512.0f);

    // d_ws is poisoned (0xAA) before every call: zero the buckets
    hipMemsetAsync(acc, 0, 48 * 16 * sizeof(float), stream);

    dim3 block(128);
    dim3 grid(8, 16, 48);                           // 6144 blocks, 2 waves each
    ssim_kernel<<<grid, block, 0, stream>>>(img1, img2, window, acc);
    ssim_finalize<<<1, 64, 0, stream>>>(acc, out, invN);
}